// Round 1
// baseline (15908.305 us; speedup 1.0000x reference)
//
#include <hip/hip_runtime.h>
#include <hip/hip_bf16.h>

namespace {

constexpr int B = 16, T = 1024, E = 512, H = 8, L = 6, V = 32, HD = 64;
constexpr int BT = B * T;            // 16384 token rows
constexpr long S = (long)BT * E;     // floats per activation buffer

// ---------------------------------------------------------------- embed ----
__global__ void embed_kernel(const int* __restrict__ tokens,
                             const float* __restrict__ emb,
                             const float* __restrict__ pos,
                             float* __restrict__ x) {
  int idx = blockIdx.x * blockDim.x + threadIdx.x;   // float4 index
  constexpr int TOT = BT * (E / 4);
  if (idx >= TOT) return;
  int row = idx >> 7;            // / (E/4 = 128)
  int c4  = idx & 127;
  int t   = row & (T - 1);
  int tok = tokens[row];
  float4 a = reinterpret_cast<const float4*>(emb + (long)tok * E)[c4];
  float4 p = reinterpret_cast<const float4*>(pos + (long)t * E)[c4];
  float4 r;
  r.x = a.x + p.x; r.y = a.y + p.y; r.z = a.z + p.z; r.w = a.w + p.w;
  reinterpret_cast<float4*>(x + (long)row * E)[c4] = r;
}

// ------------------------------------------------------------ layernorm ----
// one 128-thread block per row of 512; each thread owns one float4
__global__ __launch_bounds__(128)
void ln_kernel(const float* __restrict__ x, const float* __restrict__ g,
               const float* __restrict__ b, float* __restrict__ out) {
  int row = blockIdx.x;
  int tid = threadIdx.x;
  float4 v = reinterpret_cast<const float4*>(x + (long)row * E)[tid];
  float s = v.x + v.y + v.z + v.w;
  #pragma unroll
  for (int off = 32; off > 0; off >>= 1) s += __shfl_down(s, off, 64);
  __shared__ float r1[2], r2[2];
  int lane = tid & 63, wid = tid >> 6;
  if (lane == 0) r1[wid] = s;
  __syncthreads();
  float mean = (r1[0] + r1[1]) * (1.0f / E);
  float4 d;
  d.x = v.x - mean; d.y = v.y - mean; d.z = v.z - mean; d.w = v.w - mean;
  float s2 = d.x * d.x + d.y * d.y + d.z * d.z + d.w * d.w;
  #pragma unroll
  for (int off = 32; off > 0; off >>= 1) s2 += __shfl_down(s2, off, 64);
  if (lane == 0) r2[wid] = s2;
  __syncthreads();
  float rstd = rsqrtf((r2[0] + r2[1]) * (1.0f / E) + 1e-5f);
  float4 gg = reinterpret_cast<const float4*>(g)[tid];
  float4 bb = reinterpret_cast<const float4*>(b)[tid];
  float4 o;
  o.x = d.x * rstd * gg.x + bb.x;
  o.y = d.y * rstd * gg.y + bb.y;
  o.z = d.z * rstd * gg.z + bb.z;
  o.w = d.w * rstd * gg.w + bb.w;
  reinterpret_cast<float4*>(out + (long)row * E)[tid] = o;
}

// ----------------------------------------------------------------- gemm ----
// C[M,N] = A[M,K] @ Bw with per-64-column weight panels:
//   element (k, n_local) of column-panel p = blockIdx.y lives at
//   Bw[p*panel_stride + k*ldb + n_local]
//   row-major [K][N] weights: panel_stride=64, ldb=N
//   Wq/Wk/Wv [H][E][64]:      panel_stride=E*64, ldb=64  (head == panel)
// MODE 0: C=acc   1: C=acc+bias+res   2: C=relu(acc+bias)
template <int MODE>
__global__ __launch_bounds__(256)
void gemm_kernel(const float* __restrict__ A, const float* __restrict__ Bw,
                 const float* __restrict__ bias, const float* __restrict__ res,
                 float* __restrict__ C, int M, int N, int K, int ldb,
                 long panel_stride) {
  constexpr int BM = 64, BN = 64, BK = 32;
  __shared__ float As[BK][BM + 4];   // transposed A tile, rows 16B-aligned
  __shared__ float Bs[BK][BN + 4];
  const int bm = blockIdx.x * BM;
  const int bn = blockIdx.y * BN;
  const float* Bp = Bw + (long)blockIdx.y * panel_stride;
  const int tid = threadIdx.x;
  const int tx = tid & 15, ty = tid >> 4;
  float acc[4][4] = {};
  for (int k0 = 0; k0 < K; k0 += BK) {
    #pragma unroll
    for (int i = 0; i < 2; i++) {            // A tile: 64x32
      int f4 = tid + i * 256;
      int r = f4 >> 3, c4 = f4 & 7;
      float4 av =
          reinterpret_cast<const float4*>(A + (long)(bm + r) * K + k0)[c4];
      As[c4 * 4 + 0][r] = av.x;
      As[c4 * 4 + 1][r] = av.y;
      As[c4 * 4 + 2][r] = av.z;
      As[c4 * 4 + 3][r] = av.w;
    }
    #pragma unroll
    for (int i = 0; i < 2; i++) {            // B tile: 32x64
      int f4 = tid + i * 256;
      int r = f4 >> 4, c4 = f4 & 15;
      float4 bv =
          reinterpret_cast<const float4*>(Bp + (long)(k0 + r) * ldb)[c4];
      reinterpret_cast<float4*>(&Bs[r][c4 * 4])[0] = bv;
    }
    __syncthreads();
    #pragma unroll
    for (int k = 0; k < BK; k++) {
      float4 a = reinterpret_cast<const float4*>(&As[k][ty * 4])[0];
      float4 w = reinterpret_cast<const float4*>(&Bs[k][tx * 4])[0];
      acc[0][0] += a.x * w.x; acc[0][1] += a.x * w.y;
      acc[0][2] += a.x * w.z; acc[0][3] += a.x * w.w;
      acc[1][0] += a.y * w.x; acc[1][1] += a.y * w.y;
      acc[1][2] += a.y * w.z; acc[1][3] += a.y * w.w;
      acc[2][0] += a.z * w.x; acc[2][1] += a.z * w.y;
      acc[2][2] += a.z * w.z; acc[2][3] += a.z * w.w;
      acc[3][0] += a.w * w.x; acc[3][1] += a.w * w.y;
      acc[3][2] += a.w * w.z; acc[3][3] += a.w * w.w;
    }
    __syncthreads();
  }
  #pragma unroll
  for (int i = 0; i < 4; i++) {
    int gm = bm + ty * 4 + i;
    int gn = bn + tx * 4;
    float4 r;
    r.x = acc[i][0]; r.y = acc[i][1]; r.z = acc[i][2]; r.w = acc[i][3];
    if (MODE >= 1) {
      float4 bi = reinterpret_cast<const float4*>(bias + gn)[0];
      r.x += bi.x; r.y += bi.y; r.z += bi.z; r.w += bi.w;
    }
    if (MODE == 1) {
      float4 rs = reinterpret_cast<const float4*>(res + (long)gm * N + gn)[0];
      r.x += rs.x; r.y += rs.y; r.z += rs.z; r.w += rs.w;
    }
    if (MODE == 2) {
      r.x = fmaxf(r.x, 0.f); r.y = fmaxf(r.y, 0.f);
      r.z = fmaxf(r.z, 0.f); r.w = fmaxf(r.w, 0.f);
    }
    reinterpret_cast<float4*>(C + (long)gm * N + gn)[0] = r;
  }
}

// ------------------------------------------------------------ attention ----
// one wave per 64 query rows of one (b,h); lane = query row; online softmax.
// q/k/v stored as [B*T][E] with head h at column h*64. NOTE: no 1/sqrt(d).
__global__ __launch_bounds__(64)
void attn_kernel(const float* __restrict__ q, const float* __restrict__ k,
                 const float* __restrict__ v, float* __restrict__ o) {
  const int b = blockIdx.z, h = blockIdx.y, tile = blockIdx.x;
  const int t = tile * 64 + threadIdx.x;
  const float* qr = q + ((long)(b * T + t) * E + h * HD);
  float4 qreg[16];
  #pragma unroll
  for (int i = 0; i < 16; i++) qreg[i] = reinterpret_cast<const float4*>(qr)[i];
  float4 oacc[16] = {};
  float m = -1e30f, l = 0.f;
  const int smax = tile * 64 + 63;
  const float* kb = k + ((long)b * T) * E + h * HD;
  const float* vb = v + ((long)b * T) * E + h * HD;
  for (int s = 0; s <= smax; s++) {
    const float4* kr = reinterpret_cast<const float4*>(kb + (long)s * E);
    float dot = 0.f;
    #pragma unroll
    for (int i = 0; i < 16; i++) {
      float4 kv = kr[i];
      dot += qreg[i].x * kv.x + qreg[i].y * kv.y + qreg[i].z * kv.z +
             qreg[i].w * kv.w;
    }
    if (s <= t) {
      float mn = fmaxf(m, dot);
      float scale = __expf(m - mn);
      float p = __expf(dot - mn);
      l = l * scale + p;
      const float4* vr = reinterpret_cast<const float4*>(vb + (long)s * E);
      #pragma unroll
      for (int i = 0; i < 16; i++) {
        float4 vv = vr[i];
        oacc[i].x = oacc[i].x * scale + p * vv.x;
        oacc[i].y = oacc[i].y * scale + p * vv.y;
        oacc[i].z = oacc[i].z * scale + p * vv.z;
        oacc[i].w = oacc[i].w * scale + p * vv.w;
      }
      m = mn;
    }
  }
  float inv = 1.0f / l;
  float* orow = o + ((long)(b * T + t) * E + h * HD);
  #pragma unroll
  for (int i = 0; i < 16; i++) {
    float4 r = oacc[i];
    r.x *= inv; r.y *= inv; r.z *= inv; r.w *= inv;
    reinterpret_cast<float4*>(orow)[i] = r;
  }
}

// --------------------------------------------------------------- logits ----
// N=32 tail GEMM: block = 256 threads handles 8 rows, thread (r, col)
__global__ __launch_bounds__(256)
void logits_kernel(const float* __restrict__ xf, const float* __restrict__ Wf,
                   const float* __restrict__ bf, float* __restrict__ out) {
  __shared__ float xs[8][E];
  const int row0 = blockIdx.x * 8;
  #pragma unroll
  for (int i = 0; i < 4; i++) {
    int f4 = threadIdx.x + i * 256;
    int r = f4 >> 7, c4 = f4 & 127;
    reinterpret_cast<float4*>(&xs[r][0])[c4] =
        reinterpret_cast<const float4*>(xf + (long)(row0 + r) * E)[c4];
  }
  __syncthreads();
  const int r = threadIdx.x >> 5, c = threadIdx.x & 31;
  float acc = 0.f;
  for (int e = 0; e < E; e++) acc += xs[r][e] * Wf[e * V + c];
  out[(long)(row0 + r) * V + c] = acc + bf[c];
}

}  // namespace

// ------------------------------------------------------------- launcher ----
extern "C" void kernel_launch(void* const* d_in, const int* in_sizes, int n_in,
                              void* d_out, int out_size, void* d_ws,
                              size_t ws_size, hipStream_t stream) {
  const int*   tokens = (const int*)d_in[0];
  const float* emb    = (const float*)d_in[1];
  const float* pos    = (const float*)d_in[2];
  const float* Wq     = (const float*)d_in[3];
  const float* Wk     = (const float*)d_in[4];
  const float* Wv     = (const float*)d_in[5];
  const float* Wo     = (const float*)d_in[6];
  const float* bo     = (const float*)d_in[7];
  const float* ln1g   = (const float*)d_in[8];
  const float* ln1b   = (const float*)d_in[9];
  const float* ln2g   = (const float*)d_in[10];
  const float* ln2b   = (const float*)d_in[11];
  const float* W1     = (const float*)d_in[12];
  const float* b1     = (const float*)d_in[13];
  const float* W2     = (const float*)d_in[14];
  const float* b2     = (const float*)d_in[15];
  const float* lnfg   = (const float*)d_in[16];
  const float* lnfb   = (const float*)d_in[17];
  const float* Wf     = (const float*)d_in[18];
  const float* bf     = (const float*)d_in[19];
  float* out = (float*)d_out;

  // workspace: 5 activation buffers of [BT][E] f32 (~168 MB total)
  float* x  = (float*)d_ws;
  float* h  = x + S;    // LN out / attn out / final LN out
  float* qb = h + S;    // Q, then MLP intermediate
  float* kb = qb + S;
  float* vb = kb + S;

  embed_kernel<<<(BT * (E / 4) + 255) / 256, 256, 0, stream>>>(tokens, emb,
                                                               pos, x);

  const dim3 gg(BT / 64, E / 64);       // 256 x 8 blocks
  const dim3 ga(T / 64, H, B);          // attention grid

  for (int l = 0; l < L; l++) {
    const long wOff = (long)l * E * E;
    ln_kernel<<<BT, 128, 0, stream>>>(x, ln1g + l * E, ln1b + l * E, h);
    gemm_kernel<0><<<gg, 256, 0, stream>>>(h, Wq + (long)l * H * E * HD,
                                           nullptr, nullptr, qb, BT, E, E,
                                           HD, (long)E * HD);
    gemm_kernel<0><<<gg, 256, 0, stream>>>(h, Wk + (long)l * H * E * HD,
                                           nullptr, nullptr, kb, BT, E, E,
                                           HD, (long)E * HD);
    gemm_kernel<0><<<gg, 256, 0, stream>>>(h, Wv + (long)l * H * E * HD,
                                           nullptr, nullptr, vb, BT, E, E,
                                           HD, (long)E * HD);
    attn_kernel<<<ga, 64, 0, stream>>>(qb, kb, vb, h);
    gemm_kernel<1><<<gg, 256, 0, stream>>>(h, Wo + wOff, bo + l * E, x, x,
                                           BT, E, E, E, 64);
    ln_kernel<<<BT, 128, 0, stream>>>(x, ln2g + l * E, ln2b + l * E, h);
    gemm_kernel<2><<<gg, 256, 0, stream>>>(h, W1 + wOff, b1 + l * E, nullptr,
                                           qb, BT, E, E, E, 64);
    gemm_kernel<1><<<gg, 256, 0, stream>>>(qb, W2 + wOff, b2 + l * E, x, x,
                                           BT, E, E, E, 64);
  }

  ln_kernel<<<BT, 128, 0, stream>>>(x, lnfg, lnfb, h);
  logits_kernel<<<BT / 8, 256, 0, stream>>>(h, Wf, bf, out);
}

// Round 2
// 8852.534 us; speedup vs baseline: 1.7970x; 1.7970x over previous
//
#include <hip/hip_runtime.h>
#include <hip/hip_bf16.h>
#include <type_traits>

namespace {

constexpr int B = 16, T = 1024, E = 512, H = 8, L = 6, V = 32, HD = 64;
constexpr int BT = B * T;            // 16384 token rows
constexpr long S = (long)BT * E;     // floats per activation buffer

// ---------------------------------------------------------------- embed ----
__global__ void embed_kernel(const int* __restrict__ tokens,
                             const float* __restrict__ emb,
                             const float* __restrict__ pos,
                             float* __restrict__ x) {
  int idx = blockIdx.x * blockDim.x + threadIdx.x;   // float4 index
  constexpr int TOT = BT * (E / 4);
  if (idx >= TOT) return;
  int row = idx >> 7;            // / (E/4 = 128)
  int c4  = idx & 127;
  int t   = row & (T - 1);
  int tok = tokens[row];
  float4 a = reinterpret_cast<const float4*>(emb + (long)tok * E)[c4];
  float4 p = reinterpret_cast<const float4*>(pos + (long)t * E)[c4];
  float4 r;
  r.x = a.x + p.x; r.y = a.y + p.y; r.z = a.z + p.z; r.w = a.w + p.w;
  reinterpret_cast<float4*>(x + (long)row * E)[c4] = r;
}

// ------------------------------------------------------------ layernorm ----
__global__ __launch_bounds__(128)
void ln_kernel(const float* __restrict__ x, const float* __restrict__ g,
               const float* __restrict__ b, float* __restrict__ out) {
  int row = blockIdx.x;
  int tid = threadIdx.x;
  float4 v = reinterpret_cast<const float4*>(x + (long)row * E)[tid];
  float s = v.x + v.y + v.z + v.w;
  #pragma unroll
  for (int off = 32; off > 0; off >>= 1) s += __shfl_down(s, off, 64);
  __shared__ float r1[2], r2[2];
  int lane = tid & 63, wid = tid >> 6;
  if (lane == 0) r1[wid] = s;
  __syncthreads();
  float mean = (r1[0] + r1[1]) * (1.0f / E);
  float4 d;
  d.x = v.x - mean; d.y = v.y - mean; d.z = v.z - mean; d.w = v.w - mean;
  float s2 = d.x * d.x + d.y * d.y + d.z * d.z + d.w * d.w;
  #pragma unroll
  for (int off = 32; off > 0; off >>= 1) s2 += __shfl_down(s2, off, 64);
  if (lane == 0) r2[wid] = s2;
  __syncthreads();
  float rstd = rsqrtf((r2[0] + r2[1]) * (1.0f / E) + 1e-5f);
  float4 gg = reinterpret_cast<const float4*>(g)[tid];
  float4 bb = reinterpret_cast<const float4*>(b)[tid];
  float4 o;
  o.x = d.x * rstd * gg.x + bb.x;
  o.y = d.y * rstd * gg.y + bb.y;
  o.z = d.z * rstd * gg.z + bb.z;
  o.w = d.w * rstd * gg.w + bb.w;
  reinterpret_cast<float4*>(out + (long)row * E)[tid] = o;
}

// ----------------------------------------------------------------- gemm ----
// (unchanged from baseline)
template <int MODE>
__global__ __launch_bounds__(256)
void gemm_kernel(const float* __restrict__ A, const float* __restrict__ Bw,
                 const float* __restrict__ bias, const float* __restrict__ res,
                 float* __restrict__ C, int M, int N, int K, int ldb,
                 long panel_stride) {
  constexpr int BM = 64, BN = 64, BK = 32;
  __shared__ float As[BK][BM + 4];
  __shared__ float Bs[BK][BN + 4];
  const int bm = blockIdx.x * BM;
  const int bn = blockIdx.y * BN;
  const float* Bp = Bw + (long)blockIdx.y * panel_stride;
  const int tid = threadIdx.x;
  const int tx = tid & 15, ty = tid >> 4;
  float acc[4][4] = {};
  for (int k0 = 0; k0 < K; k0 += BK) {
    #pragma unroll
    for (int i = 0; i < 2; i++) {
      int f4 = tid + i * 256;
      int r = f4 >> 3, c4 = f4 & 7;
      float4 av =
          reinterpret_cast<const float4*>(A + (long)(bm + r) * K + k0)[c4];
      As[c4 * 4 + 0][r] = av.x;
      As[c4 * 4 + 1][r] = av.y;
      As[c4 * 4 + 2][r] = av.z;
      As[c4 * 4 + 3][r] = av.w;
    }
    #pragma unroll
    for (int i = 0; i < 2; i++) {
      int f4 = tid + i * 256;
      int r = f4 >> 4, c4 = f4 & 15;
      float4 bv =
          reinterpret_cast<const float4*>(Bp + (long)(k0 + r) * ldb)[c4];
      reinterpret_cast<float4*>(&Bs[r][c4 * 4])[0] = bv;
    }
    __syncthreads();
    #pragma unroll
    for (int k = 0; k < BK; k++) {
      float4 a = reinterpret_cast<const float4*>(&As[k][ty * 4])[0];
      float4 w = reinterpret_cast<const float4*>(&Bs[k][tx * 4])[0];
      acc[0][0] += a.x * w.x; acc[0][1] += a.x * w.y;
      acc[0][2] += a.x * w.z; acc[0][3] += a.x * w.w;
      acc[1][0] += a.y * w.x; acc[1][1] += a.y * w.y;
      acc[1][2] += a.y * w.z; acc[1][3] += a.y * w.w;
      acc[2][0] += a.z * w.x; acc[2][1] += a.z * w.y;
      acc[2][2] += a.z * w.z; acc[2][3] += a.z * w.w;
      acc[3][0] += a.w * w.x; acc[3][1] += a.w * w.y;
      acc[3][2] += a.w * w.z; acc[3][3] += a.w * w.w;
    }
    __syncthreads();
  }
  #pragma unroll
  for (int i = 0; i < 4; i++) {
    int gm = bm + ty * 4 + i;
    int gn = bn + tx * 4;
    float4 r;
    r.x = acc[i][0]; r.y = acc[i][1]; r.z = acc[i][2]; r.w = acc[i][3];
    if (MODE >= 1) {
      float4 bi = reinterpret_cast<const float4*>(bias + gn)[0];
      r.x += bi.x; r.y += bi.y; r.z += bi.z; r.w += bi.w;
    }
    if (MODE == 1) {
      float4 rs = reinterpret_cast<const float4*>(res + (long)gm * N + gn)[0];
      r.x += rs.x; r.y += rs.y; r.z += rs.z; r.w += rs.w;
    }
    if (MODE == 2) {
      r.x = fmaxf(r.x, 0.f); r.y = fmaxf(r.y, 0.f);
      r.z = fmaxf(r.z, 0.f); r.w = fmaxf(r.w, 0.f);
    }
    reinterpret_cast<float4*>(C + (long)gm * N + gn)[0] = r;
  }
}

// ------------------------------------------------------------ attention ----
// Block = 128 threads (2 waves), 128 query rows/block. Wave = 16 row-groups
// x 4 dim-parts; each lane owns 4 query rows x 16 dims. K/V staged in LDS
// in 64-step chunks shared by both waves. Online softmax with deferred
// rescale (THR=8). NOTE: reference applies NO 1/sqrt(d) scaling.
__global__ __launch_bounds__(128, 2)
void attn_kernel(const float* __restrict__ q, const float* __restrict__ k,
                 const float* __restrict__ v, float* __restrict__ o) {
  const int b = blockIdx.z, h = blockIdx.y;
  const int qt = (gridDim.x - 1) - blockIdx.x;   // longest blocks first
  const int tid = threadIdx.x;
  const int wid = tid >> 6, lane = tid & 63;
  const int grp = lane >> 2, part = lane & 3;
  const int wbase = qt * 128 + wid * 64;         // wave's first row
  const int row0 = wbase + grp * 4;              // lane's rows row0..row0+3
  const int dchunk = wbase >> 6;                 // wave's diagonal chunk

  __shared__ float Ks[64][HD];   // 16 KiB
  __shared__ float Vs[64][HD];   // 16 KiB

  const long bh = (long)b * T;
  float4 qf[4][4];
  #pragma unroll
  for (int r = 0; r < 4; ++r) {
    const float4* qp = reinterpret_cast<const float4*>(
        q + ((long)(bh + row0 + r) * E + h * HD + part * 16));
    #pragma unroll
    for (int i = 0; i < 4; ++i) qf[r][i] = qp[i];
  }
  float4 oa[4][4] = {};
  float m[4] = {-1e30f, -1e30f, -1e30f, -1e30f};
  float l[4] = {0.f, 0.f, 0.f, 0.f};

  const float* kb = k + (bh * E + h * HD);
  const float* vb = v + (bh * E + h * HD);

  auto run_chunk = [&](auto masked_t) {
    constexpr bool MASKED = decltype(masked_t)::value;
    #pragma unroll 1
    for (int ss = 0; ss < 64; ++ss) {
      float4 kf[4];
      #pragma unroll
      for (int i = 0; i < 4; ++i)
        kf[i] = reinterpret_cast<const float4*>(&Ks[ss][part * 16])[i];
      float d[4];
      #pragma unroll
      for (int r = 0; r < 4; ++r) {
        float t = qf[r][0].x * kf[0].x + qf[r][0].y * kf[0].y +
                  qf[r][0].z * kf[0].z + qf[r][0].w * kf[0].w;
        t += qf[r][1].x * kf[1].x + qf[r][1].y * kf[1].y +
             qf[r][1].z * kf[1].z + qf[r][1].w * kf[1].w;
        t += qf[r][2].x * kf[2].x + qf[r][2].y * kf[2].y +
             qf[r][2].z * kf[2].z + qf[r][2].w * kf[2].w;
        t += qf[r][3].x * kf[3].x + qf[r][3].y * kf[3].y +
             qf[r][3].z * kf[3].z + qf[r][3].w * kf[3].w;
        d[r] = t;
      }
      #pragma unroll
      for (int r = 0; r < 4; ++r) {
        float t = d[r];
        t += __shfl_xor(t, 1, 64);
        t += __shfl_xor(t, 2, 64);
        d[r] = t;
      }
      float4 vf[4];
      #pragma unroll
      for (int i = 0; i < 4; ++i)
        vf[i] = reinterpret_cast<const float4*>(&Vs[ss][part * 16])[i];
      #pragma unroll
      for (int r = 0; r < 4; ++r) {
        float dr = d[r];
        bool valid = true;
        if constexpr (MASKED) valid = (ss <= grp * 4 + r);  // s <= row
        if (valid && dr > m[r] + 8.f) {      // deferred rescale (rare)
          float sc = __expf(m[r] - dr);
          l[r] *= sc;
          #pragma unroll
          for (int i = 0; i < 4; ++i) {
            oa[r][i].x *= sc; oa[r][i].y *= sc;
            oa[r][i].z *= sc; oa[r][i].w *= sc;
          }
          m[r] = dr;
        }
        float p = __expf(dr - m[r]);
        if constexpr (MASKED) p = valid ? p : 0.f;
        l[r] += p;
        #pragma unroll
        for (int i = 0; i < 4; ++i) {
          oa[r][i].x += p * vf[i].x; oa[r][i].y += p * vf[i].y;
          oa[r][i].z += p * vf[i].z; oa[r][i].w += p * vf[i].w;
        }
      }
    }
  };

  const int nch = 2 * qt + 2;          // chunks this block must stage
  for (int c = 0; c < nch; ++c) {
    const int s0 = c * 64;
    #pragma unroll
    for (int ppass = 0; ppass < 8; ++ppass) {   // stage K,V [64][64]
      int idx = ppass * 128 + tid;              // float4 index 0..1023
      int rr = idx >> 4, c4 = idx & 15;
      reinterpret_cast<float4*>(&Ks[rr][0])[c4] =
          reinterpret_cast<const float4*>(kb + (long)(s0 + rr) * E)[c4];
      reinterpret_cast<float4*>(&Vs[rr][0])[c4] =
          reinterpret_cast<const float4*>(vb + (long)(s0 + rr) * E)[c4];
    }
    __syncthreads();
    if (c < dchunk)       run_chunk(std::false_type{});
    else if (c == dchunk) run_chunk(std::true_type{});
    __syncthreads();
  }

  #pragma unroll
  for (int r = 0; r < 4; ++r) {
    float inv = 1.0f / l[r];
    float4* op = reinterpret_cast<float4*>(
        o + ((long)(bh + row0 + r) * E + h * HD + part * 16));
    #pragma unroll
    for (int i = 0; i < 4; ++i) {
      float4 t = oa[r][i];
      t.x *= inv; t.y *= inv; t.z *= inv; t.w *= inv;
      op[i] = t;
    }
  }
}

// --------------------------------------------------------------- logits ----
__global__ __launch_bounds__(256)
void logits_kernel(const float* __restrict__ xf, const float* __restrict__ Wf,
                   const float* __restrict__ bf, float* __restrict__ out) {
  __shared__ float xs[8][E];
  const int row0 = blockIdx.x * 8;
  #pragma unroll
  for (int i = 0; i < 4; i++) {
    int f4 = threadIdx.x + i * 256;
    int r = f4 >> 7, c4 = f4 & 127;
    reinterpret_cast<float4*>(&xs[r][0])[c4] =
        reinterpret_cast<const float4*>(xf + (long)(row0 + r) * E)[c4];
  }
  __syncthreads();
  const int r = threadIdx.x >> 5, c = threadIdx.x & 31;
  float acc = 0.f;
  for (int e = 0; e < E; e++) acc += xs[r][e] * Wf[e * V + c];
  out[(long)(row0 + r) * V + c] = acc + bf[c];
}

}  // namespace

// ------------------------------------------------------------- launcher ----
extern "C" void kernel_launch(void* const* d_in, const int* in_sizes, int n_in,
                              void* d_out, int out_size, void* d_ws,
                              size_t ws_size, hipStream_t stream) {
  const int*   tokens = (const int*)d_in[0];
  const float* emb    = (const float*)d_in[1];
  const float* pos    = (const float*)d_in[2];
  const float* Wq     = (const float*)d_in[3];
  const float* Wk     = (const float*)d_in[4];
  const float* Wv     = (const float*)d_in[5];
  const float* Wo     = (const float*)d_in[6];
  const float* bo     = (const float*)d_in[7];
  const float* ln1g   = (const float*)d_in[8];
  const float* ln1b   = (const float*)d_in[9];
  const float* ln2g   = (const float*)d_in[10];
  const float* ln2b   = (const float*)d_in[11];
  const float* W1     = (const float*)d_in[12];
  const float* b1     = (const float*)d_in[13];
  const float* W2     = (const float*)d_in[14];
  const float* b2     = (const float*)d_in[15];
  const float* lnfg   = (const float*)d_in[16];
  const float* lnfb   = (const float*)d_in[17];
  const float* Wf     = (const float*)d_in[18];
  const float* bf     = (const float*)d_in[19];
  float* out = (float*)d_out;

  float* x  = (float*)d_ws;
  float* h  = x + S;
  float* qb = h + S;
  float* kb = qb + S;
  float* vb = kb + S;

  embed_kernel<<<(BT * (E / 4) + 255) / 256, 256, 0, stream>>>(tokens, emb,
                                                               pos, x);

  const dim3 gg(BT / 64, E / 64);
  const dim3 ga(T / 128, H, B);          // 8 x 8 x 16 blocks, 128 thr

  for (int l = 0; l < L; l++) {
    const long wOff = (long)l * E * E;
    ln_kernel<<<BT, 128, 0, stream>>>(x, ln1g + l * E, ln1b + l * E, h);
    gemm_kernel<0><<<gg, 256, 0, stream>>>(h, Wq + (long)l * H * E * HD,
                                           nullptr, nullptr, qb, BT, E, E,
                                           HD, (long)E * HD);
    gemm_kernel<0><<<gg, 256, 0, stream>>>(h, Wk + (long)l * H * E * HD,
                                           nullptr, nullptr, kb, BT, E, E,
                                           HD, (long)E * HD);
    gemm_kernel<0><<<gg, 256, 0, stream>>>(h, Wv + (long)l * H * E * HD,
                                           nullptr, nullptr, vb, BT, E, E,
                                           HD, (long)E * HD);
    attn_kernel<<<ga, 128, 0, stream>>>(qb, kb, vb, h);
    gemm_kernel<1><<<gg, 256, 0, stream>>>(h, Wo + wOff, bo + l * E, x, x,
                                           BT, E, E, E, 64);
    ln_kernel<<<BT, 128, 0, stream>>>(x, ln2g + l * E, ln2b + l * E, h);
    gemm_kernel<2><<<gg, 256, 0, stream>>>(h, W1 + wOff, b1 + l * E, nullptr,
                                           qb, BT, E, E, E, 64);
    gemm_kernel<1><<<gg, 256, 0, stream>>>(qb, W2 + wOff, b2 + l * E, x, x,
                                           BT, E, E, E, 64);
  }

  ln_kernel<<<BT, 128, 0, stream>>>(x, lnfg, lnfb, h);
  logits_kernel<<<BT / 8, 256, 0, stream>>>(h, Wf, bf, out);
}

// Round 5
// 2645.130 us; speedup vs baseline: 6.0142x; 3.3467x over previous
//
#include <hip/hip_runtime.h>
#include <hip/hip_bf16.h>

namespace {

constexpr int B = 16, T = 1024, E = 512, H = 8, L = 6, V = 32, HD = 64;
constexpr int BT = B * T;
constexpr long S = (long)BT * E;

typedef __attribute__((ext_vector_type(8))) short bf16x8;
typedef __attribute__((ext_vector_type(4))) float f32x4;

__device__ inline float b2f(ushort u) {
  union { unsigned u; float f; } v; v.u = (unsigned)u << 16; return v.f;
}
__device__ inline ushort f2b(float f) {   // RNE truncate fp32->bf16
  union { float f; unsigned u; } v; v.f = f;
  unsigned r = v.u + 0x7FFFu + ((v.u >> 16) & 1u);
  return (ushort)(r >> 16);
}
__device__ inline void gl_lds16(const ushort* g, ushort* lds) {
  __builtin_amdgcn_global_load_lds(
      (const __attribute__((address_space(1))) void*)g,
      (__attribute__((address_space(3))) void*)lds, 16, 0, 0);
}

// ---------------------------------------------------------------- embed ----
__global__ void embed_kernel(const int* __restrict__ tokens,
                             const float* __restrict__ emb,
                             const float* __restrict__ pos,
                             float* __restrict__ x) {
  int idx = blockIdx.x * blockDim.x + threadIdx.x;
  constexpr int TOT = BT * (E / 4);
  if (idx >= TOT) return;
  int row = idx >> 7, c4 = idx & 127;
  int t = row & (T - 1);
  int tok = tokens[row];
  float4 a = reinterpret_cast<const float4*>(emb + (long)tok * E)[c4];
  float4 p = reinterpret_cast<const float4*>(pos + (long)t * E)[c4];
  float4 r;
  r.x = a.x + p.x; r.y = a.y + p.y; r.z = a.z + p.z; r.w = a.w + p.w;
  reinterpret_cast<float4*>(x + (long)row * E)[c4] = r;
}

// --------------------------------------------- weight transpose -> bf16 ----
__global__ __launch_bounds__(256)
void wconv_kernel(const float* __restrict__ in, ushort* __restrict__ out,
                  int K, int Nn) {
  const long pbase = (long)blockIdx.z * K * Nn;
  __shared__ float t[32][33];
  const int k0 = blockIdx.x * 32, n0 = blockIdx.y * 32;
  const int tid = threadIdx.x, r = tid >> 5, c = tid & 31;
  #pragma unroll
  for (int i = 0; i < 4; i++)
    t[r + i * 8][c] = in[pbase + (long)(k0 + r + i * 8) * Nn + n0 + c];
  __syncthreads();
  #pragma unroll
  for (int i = 0; i < 4; i++)
    out[pbase + (long)(n0 + r + i * 8) * K + k0 + c] = f2b(t[c][r + i * 8]);
}

// ------------------------------------------------- layernorm (bf16 out) ----
__global__ __launch_bounds__(128)
void ln_kernel(const float* __restrict__ x, const float* __restrict__ g,
               const float* __restrict__ b, ushort* __restrict__ out) {
  int row = blockIdx.x, tid = threadIdx.x;
  float4 v = reinterpret_cast<const float4*>(x + (long)row * E)[tid];
  float s = v.x + v.y + v.z + v.w;
  #pragma unroll
  for (int off = 32; off > 0; off >>= 1) s += __shfl_down(s, off, 64);
  __shared__ float r1[2], r2[2];
  int lane = tid & 63, wid = tid >> 6;
  if (lane == 0) r1[wid] = s;
  __syncthreads();
  float mean = (r1[0] + r1[1]) * (1.0f / E);
  float4 d;
  d.x = v.x - mean; d.y = v.y - mean; d.z = v.z - mean; d.w = v.w - mean;
  float s2 = d.x * d.x + d.y * d.y + d.z * d.z + d.w * d.w;
  #pragma unroll
  for (int off = 32; off > 0; off >>= 1) s2 += __shfl_down(s2, off, 64);
  if (lane == 0) r2[wid] = s2;
  __syncthreads();
  float rstd = rsqrtf((r2[0] + r2[1]) * (1.0f / E) + 1e-5f);
  float4 gg = reinterpret_cast<const float4*>(g)[tid];
  float4 bb = reinterpret_cast<const float4*>(b)[tid];
  ushort4 o;
  o.x = f2b(d.x * rstd * gg.x + bb.x);
  o.y = f2b(d.y * rstd * gg.y + bb.y);
  o.z = f2b(d.z * rstd * gg.z + bb.z);
  o.w = f2b(d.w * rstd * gg.w + bb.w);
  reinterpret_cast<ushort4*>(out + (long)row * E)[tid] = o;
}

// ------------------------------------------------------------ bf16 GEMM ----
// C[M=BT][512] = A[M][512](bf16) @ Bt[512][512](bf16, pre-transposed [N][K])
// MODE 0: C=bf16(acc)  1: C=f32(acc+bias+res)  2: C=bf16(relu(acc+bias))
template <int MODE>
__global__ __launch_bounds__(256, 2)
void bgemm_kernel(const ushort* __restrict__ A, const ushort* __restrict__ Bt,
                  const float* __restrict__ bias, const float* __restrict__ res,
                  void* __restrict__ Cout) {
  constexpr int K = 512, N = 512;
  __shared__ ushort As[128][32];
  __shared__ ushort Bs[128][32];
  const int tid = threadIdx.x, lane = tid & 63, wid = tid >> 6;
  const int bm = blockIdx.x * 128, bn = blockIdx.y * 128;
  const int wm = (wid >> 1) * 64, wn = (wid & 1) * 64;
  const int lo = lane & 15, hi = lane >> 4;
  const int arow = lane >> 2, acol = (lane & 3) * 8;
  f32x4 acc[4][4] = {};
  for (int k0 = 0; k0 < K; k0 += 32) {
    #pragma unroll
    for (int i = 0; i < 2; i++) {
      int seg = wid * 2 + i;
      gl_lds16(A + (long)(bm + seg * 16 + arow) * K + k0 + acol,
               &As[seg * 16][0]);
      gl_lds16(Bt + (long)(bn + seg * 16 + arow) * K + k0 + acol,
               &Bs[seg * 16][0]);
    }
    __syncthreads();
    bf16x8 af[4], bfr[4];
    #pragma unroll
    for (int mi = 0; mi < 4; mi++)
      af[mi] = *(const bf16x8*)&As[wm + mi * 16 + lo][hi * 8];
    #pragma unroll
    for (int ni = 0; ni < 4; ni++)
      bfr[ni] = *(const bf16x8*)&Bs[wn + ni * 16 + lo][hi * 8];
    #pragma unroll
    for (int mi = 0; mi < 4; mi++)
      #pragma unroll
      for (int ni = 0; ni < 4; ni++)
        acc[mi][ni] = __builtin_amdgcn_mfma_f32_16x16x32_bf16(
            af[mi], bfr[ni], acc[mi][ni], 0, 0, 0);
    __syncthreads();
  }
  #pragma unroll
  for (int mi = 0; mi < 4; mi++) {
    #pragma unroll
    for (int ni = 0; ni < 4; ni++) {
      const int gn = bn + wn + ni * 16 + lo;
      const float bv = (MODE >= 1) ? bias[gn] : 0.f;
      #pragma unroll
      for (int r = 0; r < 4; r++) {
        const long gm = bm + wm + mi * 16 + hi * 4 + r;
        float vv = acc[mi][ni][r];
        if (MODE == 0) {
          ((ushort*)Cout)[gm * N + gn] = f2b(vv);
        } else if (MODE == 1) {
          ((float*)Cout)[gm * N + gn] = vv + bv + res[gm * N + gn];
        } else {
          ((ushort*)Cout)[gm * N + gn] = f2b(fmaxf(vv + bv, 0.f));
        }
      }
    }
  }
}

// ------------------------------------------------------- MFMA attention ----
// 2 waves/block, 64 q-rows/wave. K/V chunks of 64 staged in LDS (bf16,
// XOR-swizzled; V transposed). QK^T and PV via 16x16x32 MFMA; P through
// swizzled per-wave LDS. Online softmax; NO 1/sqrt(d) (per reference).
__global__ __launch_bounds__(128, 2)
void attn_kernel(const ushort* __restrict__ q, const ushort* __restrict__ k,
                 const ushort* __restrict__ v, ushort* __restrict__ o) {
  const int b = blockIdx.z, h = blockIdx.y;
  const int qt = (gridDim.x - 1) - blockIdx.x;   // longest first
  const int tid = threadIdx.x, wid = tid >> 6, lane = tid & 63;
  const int lo = lane & 15, hi = lane >> 4;
  const long bh = (long)b * T;
  const int qbase = qt * 128 + wid * 64;
  const int dch = qt * 2 + wid;            // this wave's diagonal chunk
  __shared__ ushort Ks[64 * 64];
  __shared__ ushort Vs[64 * 64];
  __shared__ ushort Ps[2][64 * 64];
  char* KsB = (char*)Ks;
  char* VsB = (char*)Vs;
  char* PsB = (char*)Ps[wid];

  bf16x8 qf[4][2];
  #pragma unroll
  for (int mf = 0; mf < 4; mf++)
    #pragma unroll
    for (int kh = 0; kh < 2; kh++)
      qf[mf][kh] = *(const bf16x8*)(q + (bh + qbase + mf * 16 + lo) * E +
                                    h * 64 + kh * 32 + hi * 8);
  f32x4 accO[4][4] = {};
  float m[4][4], lsum[4][4];
  #pragma unroll
  for (int a = 0; a < 4; a++)
    #pragma unroll
    for (int r = 0; r < 4; r++) { m[a][r] = -1e30f; lsum[a][r] = 0.f; }

  const ushort* kb = k + bh * E + h * 64;
  const ushort* vb = v + bh * E + h * 64;
  const int nch = qt * 2 + 2;

  for (int c = 0; c < nch; c++) {
    const long s0 = (long)c * 64;
    // ---- stage K chunk (swizzled rows): 64 rows x 8 uint4, 128 threads ----
    #pragma unroll
    for (int it = 0; it < 4; it++) {
      int idx = it * 128 + tid;                 // 0..511
      int key = idx >> 3, c8 = idx & 7;
      uint4 kv = *(const uint4*)(kb + (s0 + key) * E + c8 * 8);
      *(uint4*)(KsB + ((key * 128 + c8 * 16) ^ ((key & 7) << 4))) = kv;
    }
    // ---- stage V transposed (all 128 threads: 4key x 8dim subtiles) ----
    {
      const int key0 = (tid & 15) * 4, dim0 = (tid >> 4) * 8;
      uint4 vv[4];
      #pragma unroll
      for (int kk = 0; kk < 4; kk++)
        vv[kk] = *(const uint4*)(vb + (s0 + key0 + kk) * E + dim0);
      const ushort* pv = (const ushort*)vv;
      #pragma unroll
      for (int j = 0; j < 8; j++) {
        const int dim = dim0 + j;
        ushort4 w;
        w.x = pv[0 * 8 + j]; w.y = pv[1 * 8 + j];
        w.z = pv[2 * 8 + j]; w.w = pv[3 * 8 + j];
        *(ushort4*)(VsB + ((dim * 128 + key0 * 2) ^ ((dim & 7) << 4))) = w;
      }
    }
    __syncthreads();
    if (c <= dch) {
      const bool diag = (c == dch);
      bf16x8 kf[4][2];
      #pragma unroll
      for (int nf = 0; nf < 4; nf++)
        #pragma unroll
        for (int kh = 0; kh < 2; kh++) {
          const int key = nf * 16 + lo;
          kf[nf][kh] = *(const bf16x8*)(
              KsB + ((key * 128 + kh * 64 + hi * 16) ^ ((key & 7) << 4)));
        }
      #pragma unroll
      for (int mf = 0; mf < 4; mf++) {
        f32x4 s[4];
        #pragma unroll
        for (int nf = 0; nf < 4; nf++) {
          f32x4 z = {0.f, 0.f, 0.f, 0.f};
          z = __builtin_amdgcn_mfma_f32_16x16x32_bf16(qf[mf][0], kf[nf][0],
                                                      z, 0, 0, 0);
          z = __builtin_amdgcn_mfma_f32_16x16x32_bf16(qf[mf][1], kf[nf][1],
                                                      z, 0, 0, 0);
          s[nf] = z;
        }
        if (diag) {
          #pragma unroll
          for (int nf = 0; nf < 4; nf++)
            #pragma unroll
            for (int r = 0; r < 4; r++)
              if (nf * 16 + lo > mf * 16 + hi * 4 + r) s[nf][r] = -1e30f;
        }
        #pragma unroll
        for (int r = 0; r < 4; r++) {
          float pm = fmaxf(fmaxf(s[0][r], s[1][r]), fmaxf(s[2][r], s[3][r]));
          #pragma unroll
          for (int msk = 1; msk < 16; msk <<= 1)
            pm = fmaxf(pm, __shfl_xor(pm, msk, 64));
          const float mn = fmaxf(m[mf][r], pm);
          const float sc = __expf(m[mf][r] - mn);
          m[mf][r] = mn;
          float p0 = __expf(s[0][r] - mn), p1 = __expf(s[1][r] - mn);
          float p2 = __expf(s[2][r] - mn), p3 = __expf(s[3][r] - mn);
          lsum[mf][r] = lsum[mf][r] * sc + (p0 + p1 + p2 + p3);
          #pragma unroll
          for (int nd = 0; nd < 4; nd++) accO[mf][nd][r] *= sc;
          const int ql = mf * 16 + hi * 4 + r;
          const int swz = (ql & 7) << 4;
          *(ushort*)(PsB + ((ql * 128 + (lo) * 2) ^ swz))      = f2b(p0);
          *(ushort*)(PsB + ((ql * 128 + (16 + lo) * 2) ^ swz)) = f2b(p1);
          *(ushort*)(PsB + ((ql * 128 + (32 + lo) * 2) ^ swz)) = f2b(p2);
          *(ushort*)(PsB + ((ql * 128 + (48 + lo) * 2) ^ swz)) = f2b(p3);
        }
      }
      asm volatile("s_waitcnt lgkmcnt(0)" ::: "memory");  // P w->r, same wave
      #pragma unroll
      for (int ks = 0; ks < 2; ks++) {
        bf16x8 pa[4];
        #pragma unroll
        for (int mf = 0; mf < 4; mf++) {
          const int ql = mf * 16 + lo;
          pa[mf] = *(const bf16x8*)(
              PsB + ((ql * 128 + ks * 64 + hi * 16) ^ ((ql & 7) << 4)));
        }
        #pragma unroll
        for (int nd = 0; nd < 4; nd++) {
          const int dim = nd * 16 + lo;
          bf16x8 vf = *(const bf16x8*)(
              VsB + ((dim * 128 + ks * 64 + hi * 16) ^ ((dim & 7) << 4)));
          #pragma unroll
          for (int mf = 0; mf < 4; mf++)
            accO[mf][nd] = __builtin_amdgcn_mfma_f32_16x16x32_bf16(
                pa[mf], vf, accO[mf][nd], 0, 0, 0);
        }
      }
    }
    __syncthreads();
  }
  // ---- finalize: 1/l, stage O in LDS (reuse Ps), coalesced store ----
  #pragma unroll
  for (int mf = 0; mf < 4; mf++)
    #pragma unroll
    for (int r = 0; r < 4; r++) {
      float l = lsum[mf][r];
      #pragma unroll
      for (int msk = 1; msk < 16; msk <<= 1) l += __shfl_xor(l, msk, 64);
      lsum[mf][r] = 1.0f / l;
    }
  #pragma unroll
  for (int mf = 0; mf < 4; mf++)
    #pragma unroll
    for (int nd = 0; nd < 4; nd++)
      #pragma unroll
      for (int r = 0; r < 4; r++) {
        const int ql = mf * 16 + hi * 4 + r, dim = nd * 16 + lo;
        *(ushort*)(PsB + ql * 128 + dim * 2) =
            f2b(accO[mf][nd][r] * lsum[mf][r]);
      }
  asm volatile("s_waitcnt lgkmcnt(0)" ::: "memory");  // O w->r, same wave
  #pragma unroll
  for (int it = 0; it < 8; it++) {
    const int idx = it * 64 + lane;
    const int row = idx >> 3, c8 = idx & 7;
    uint4 val = *(const uint4*)(PsB + row * 128 + c8 * 16);
    *(uint4*)(o + (bh + qbase + row) * E + h * 64 + c8 * 8) = val;
  }
}

// --------------------------------------------------------------- logits ----
__global__ __launch_bounds__(256)
void logits_kernel(const ushort* __restrict__ xf, const ushort* __restrict__ WfT,
                   const float* __restrict__ bf, float* __restrict__ out) {
  __shared__ float xs[8][E];
  const int row0 = blockIdx.x * 8, tid = threadIdx.x;
  #pragma unroll
  for (int i = 0; i < 4; i++) {
    int idx = i * 256 + tid;
    int r = idx >> 7, c4 = idx & 127;
    ushort4 u = ((const ushort4*)(xf + (long)(row0 + r) * E))[c4];
    float4 f;
    f.x = b2f(u.x); f.y = b2f(u.y); f.z = b2f(u.z); f.w = b2f(u.w);
    *(float4*)&xs[r][c4 * 4] = f;
  }
  __syncthreads();
  const int r = tid >> 5, c = tid & 31;
  float acc = 0.f;
  for (int e8 = 0; e8 < 64; e8++) {
    uint4 w = *(const uint4*)(WfT + (long)c * E + e8 * 8);
    const ushort* ws = (const ushort*)&w;
    #pragma unroll
    for (int j = 0; j < 8; j++) acc += xs[r][e8 * 8 + j] * b2f(ws[j]);
  }
  out[(long)(row0 + r) * V + c] = acc + bf[c];
}

}  // namespace

// ------------------------------------------------------------- launcher ----
extern "C" void kernel_launch(void* const* d_in, const int* in_sizes, int n_in,
                              void* d_out, int out_size, void* d_ws,
                              size_t ws_size, hipStream_t stream) {
  const int*   tokens = (const int*)d_in[0];
  const float* emb    = (const float*)d_in[1];
  const float* pos    = (const float*)d_in[2];
  const float* Wq     = (const float*)d_in[3];
  const float* Wk     = (const float*)d_in[4];
  const float* Wv     = (const float*)d_in[5];
  const float* Wo     = (const float*)d_in[6];
  const float* bo     = (const float*)d_in[7];
  const float* ln1g   = (const float*)d_in[8];
  const float* ln1b   = (const float*)d_in[9];
  const float* ln2g   = (const float*)d_in[10];
  const float* ln2b   = (const float*)d_in[11];
  const float* W1     = (const float*)d_in[12];
  const float* b1     = (const float*)d_in[13];
  const float* W2     = (const float*)d_in[14];
  const float* b2     = (const float*)d_in[15];
  const float* lnfg   = (const float*)d_in[16];
  const float* lnfb   = (const float*)d_in[17];
  const float* Wf     = (const float*)d_in[18];
  const float* bf     = (const float*)d_in[19];
  float* out = (float*)d_out;

  // ---- workspace layout ----
  char* p = (char*)d_ws;
  float*  x   = (float*)p;           p += S * 4;          // fp32 residual
  ushort* hb  = (ushort*)p;          p += S * 2;
  ushort* qbb = (ushort*)p;          p += S * 2;
  ushort* kbb = (ushort*)p;          p += S * 2;
  ushort* vbb = (ushort*)p;          p += S * 2;
  const long WSZ = (long)L * E * E;
  ushort* wqT = (ushort*)p;          p += WSZ * 2;
  ushort* wkT = (ushort*)p;          p += WSZ * 2;
  ushort* wvT = (ushort*)p;          p += WSZ * 2;
  ushort* woT = (ushort*)p;          p += WSZ * 2;
  ushort* w1T = (ushort*)p;          p += WSZ * 2;
  ushort* w2T = (ushort*)p;          p += WSZ * 2;
  ushort* wfT = (ushort*)p;          p += (long)E * V * 2;

  // ---- weight conversion (every call; ~60 us) ----
  wconv_kernel<<<dim3(16, 2, L * H), 256, 0, stream>>>(Wq, wqT, E, HD);
  wconv_kernel<<<dim3(16, 2, L * H), 256, 0, stream>>>(Wk, wkT, E, HD);
  wconv_kernel<<<dim3(16, 2, L * H), 256, 0, stream>>>(Wv, wvT, E, HD);
  wconv_kernel<<<dim3(16, 16, L), 256, 0, stream>>>(Wo, woT, E, E);
  wconv_kernel<<<dim3(16, 16, L), 256, 0, stream>>>(W1, w1T, E, E);
  wconv_kernel<<<dim3(16, 16, L), 256, 0, stream>>>(W2, w2T, E, E);
  wconv_kernel<<<dim3(16, 1, 1), 256, 0, stream>>>(Wf, wfT, E, V);

  embed_kernel<<<(BT * (E / 4) + 255) / 256, 256, 0, stream>>>(tokens, emb,
                                                               pos, x);

  const dim3 gg(BT / 128, E / 128);   // 128 x 4
  const dim3 ga(T / 128, H, B);       // 8 x 8 x 16

  for (int l = 0; l < L; l++) {
    const long wo = (long)l * E * E;
    ln_kernel<<<BT, 128, 0, stream>>>(x, ln1g + l * E, ln1b + l * E, hb);
    bgemm_kernel<0><<<gg, 256, 0, stream>>>(hb, wqT + wo, nullptr, nullptr,
                                            qbb);
    bgemm_kernel<0><<<gg, 256, 0, stream>>>(hb, wkT + wo, nullptr, nullptr,
                                            kbb);
    bgemm_kernel<0><<<gg, 256, 0, stream>>>(hb, wvT + wo, nullptr, nullptr,
                                            vbb);
    attn_kernel<<<ga, 128, 0, stream>>>(qbb, kbb, vbb, hb);
    bgemm_kernel<1><<<gg, 256, 0, stream>>>(hb, woT + wo, bo + l * E, x, x);
    ln_kernel<<<BT, 128, 0, stream>>>(x, ln2g + l * E, ln2b + l * E, hb);
    bgemm_kernel<2><<<gg, 256, 0, stream>>>(hb, w1T + wo, b1 + l * E, nullptr,
                                            qbb);
    bgemm_kernel<1><<<gg, 256, 0, stream>>>(qbb, w2T + wo, b2 + l * E, x, x);
  }

  ln_kernel<<<BT, 128, 0, stream>>>(x, lnfg, lnfb, hb);
  logits_kernel<<<BT / 8, 256, 0, stream>>>(hb, wfT, bf, out);
}

// Round 6
// 1577.676 us; speedup vs baseline: 10.0834x; 1.6766x over previous
//
#include <hip/hip_runtime.h>
#include <hip/hip_bf16.h>

namespace {

constexpr int B = 16, T = 1024, E = 512, H = 8, L = 6, V = 32, HD = 64;
constexpr int BT = B * T;
constexpr long S = (long)BT * E;

typedef __attribute__((ext_vector_type(8))) short bf16x8;
typedef __attribute__((ext_vector_type(4))) float f32x4;

__device__ inline float b2f(ushort u) {
  union { unsigned u; float f; } v; v.u = (unsigned)u << 16; return v.f;
}
__device__ inline ushort f2b(float f) {   // RNE truncate fp32->bf16
  union { float f; unsigned u; } v; v.f = f;
  unsigned r = v.u + 0x7FFFu + ((v.u >> 16) & 1u);
  return (ushort)(r >> 16);
}
__device__ inline void gl_lds16(const ushort* g, ushort* lds) {
  __builtin_amdgcn_global_load_lds(
      (const __attribute__((address_space(1))) void*)g,
      (__attribute__((address_space(3))) void*)lds, 16, 0, 0);
}

// ---------------------------------------------------------------- embed ----
__global__ void embed_kernel(const int* __restrict__ tokens,
                             const float* __restrict__ emb,
                             const float* __restrict__ pos,
                             float* __restrict__ x) {
  int idx = blockIdx.x * blockDim.x + threadIdx.x;
  constexpr int TOT = BT * (E / 4);
  if (idx >= TOT) return;
  int row = idx >> 7, c4 = idx & 127;
  int t = row & (T - 1);
  int tok = tokens[row];
  float4 a = reinterpret_cast<const float4*>(emb + (long)tok * E)[c4];
  float4 p = reinterpret_cast<const float4*>(pos + (long)t * E)[c4];
  float4 r;
  r.x = a.x + p.x; r.y = a.y + p.y; r.z = a.z + p.z; r.w = a.w + p.w;
  reinterpret_cast<float4*>(x + (long)row * E)[c4] = r;
}

// --------------------------------------------- weight transpose -> bf16 ----
__global__ __launch_bounds__(256)
void wconv_kernel(const float* __restrict__ in, ushort* __restrict__ out,
                  int K, int Nn) {
  const long pbase = (long)blockIdx.z * K * Nn;
  __shared__ float t[32][33];
  const int k0 = blockIdx.x * 32, n0 = blockIdx.y * 32;
  const int tid = threadIdx.x, r = tid >> 5, c = tid & 31;
  #pragma unroll
  for (int i = 0; i < 4; i++)
    t[r + i * 8][c] = in[pbase + (long)(k0 + r + i * 8) * Nn + n0 + c];
  __syncthreads();
  #pragma unroll
  for (int i = 0; i < 4; i++)
    out[pbase + (long)(n0 + r + i * 8) * K + k0 + c] = f2b(t[c][r + i * 8]);
}

// ------------------------------------------------- layernorm (bf16 out) ----
__global__ __launch_bounds__(128)
void ln_kernel(const float* __restrict__ x, const float* __restrict__ g,
               const float* __restrict__ b, ushort* __restrict__ out) {
  int row = blockIdx.x, tid = threadIdx.x;
  float4 v = reinterpret_cast<const float4*>(x + (long)row * E)[tid];
  float s = v.x + v.y + v.z + v.w;
  #pragma unroll
  for (int off = 32; off > 0; off >>= 1) s += __shfl_down(s, off, 64);
  __shared__ float r1[2], r2[2];
  int lane = tid & 63, wid = tid >> 6;
  if (lane == 0) r1[wid] = s;
  __syncthreads();
  float mean = (r1[0] + r1[1]) * (1.0f / E);
  float4 d;
  d.x = v.x - mean; d.y = v.y - mean; d.z = v.z - mean; d.w = v.w - mean;
  float s2 = d.x * d.x + d.y * d.y + d.z * d.z + d.w * d.w;
  #pragma unroll
  for (int off = 32; off > 0; off >>= 1) s2 += __shfl_down(s2, off, 64);
  if (lane == 0) r2[wid] = s2;
  __syncthreads();
  float rstd = rsqrtf((r2[0] + r2[1]) * (1.0f / E) + 1e-5f);
  float4 gg = reinterpret_cast<const float4*>(g)[tid];
  float4 bb = reinterpret_cast<const float4*>(b)[tid];
  ushort4 o;
  o.x = f2b(d.x * rstd * gg.x + bb.x);
  o.y = f2b(d.y * rstd * gg.y + bb.y);
  o.z = f2b(d.z * rstd * gg.z + bb.z);
  o.w = f2b(d.w * rstd * gg.w + bb.w);
  reinterpret_cast<ushort4*>(out + (long)row * E)[tid] = o;
}

// ------------------------------------------------------------ bf16 GEMM ----
// (unchanged from round 5)
template <int MODE>
__global__ __launch_bounds__(256, 2)
void bgemm_kernel(const ushort* __restrict__ A, const ushort* __restrict__ Bt,
                  const float* __restrict__ bias, const float* __restrict__ res,
                  void* __restrict__ Cout) {
  constexpr int K = 512, N = 512;
  __shared__ ushort As[128][32];
  __shared__ ushort Bs[128][32];
  const int tid = threadIdx.x, lane = tid & 63, wid = tid >> 6;
  const int bm = blockIdx.x * 128, bn = blockIdx.y * 128;
  const int wm = (wid >> 1) * 64, wn = (wid & 1) * 64;
  const int lo = lane & 15, hi = lane >> 4;
  const int arow = lane >> 2, acol = (lane & 3) * 8;
  f32x4 acc[4][4] = {};
  for (int k0 = 0; k0 < K; k0 += 32) {
    #pragma unroll
    for (int i = 0; i < 2; i++) {
      int seg = wid * 2 + i;
      gl_lds16(A + (long)(bm + seg * 16 + arow) * K + k0 + acol,
               &As[seg * 16][0]);
      gl_lds16(Bt + (long)(bn + seg * 16 + arow) * K + k0 + acol,
               &Bs[seg * 16][0]);
    }
    __syncthreads();
    bf16x8 af[4], bfr[4];
    #pragma unroll
    for (int mi = 0; mi < 4; mi++)
      af[mi] = *(const bf16x8*)&As[wm + mi * 16 + lo][hi * 8];
    #pragma unroll
    for (int ni = 0; ni < 4; ni++)
      bfr[ni] = *(const bf16x8*)&Bs[wn + ni * 16 + lo][hi * 8];
    #pragma unroll
    for (int mi = 0; mi < 4; mi++)
      #pragma unroll
      for (int ni = 0; ni < 4; ni++)
        acc[mi][ni] = __builtin_amdgcn_mfma_f32_16x16x32_bf16(
            af[mi], bfr[ni], acc[mi][ni], 0, 0, 0);
    __syncthreads();
  }
  #pragma unroll
  for (int mi = 0; mi < 4; mi++) {
    #pragma unroll
    for (int ni = 0; ni < 4; ni++) {
      const int gn = bn + wn + ni * 16 + lo;
      const float bv = (MODE >= 1) ? bias[gn] : 0.f;
      #pragma unroll
      for (int r = 0; r < 4; r++) {
        const long gm = bm + wm + mi * 16 + hi * 4 + r;
        float vv = acc[mi][ni][r];
        if (MODE == 0) {
          ((ushort*)Cout)[gm * N + gn] = f2b(vv);
        } else if (MODE == 1) {
          ((float*)Cout)[gm * N + gn] = vv + bv + res[gm * N + gn];
        } else {
          ((ushort*)Cout)[gm * N + gn] = f2b(fmaxf(vv + bv, 0.f));
        }
      }
    }
  }
}

// ------------------------------------------------------- MFMA attention ----
// 4 waves/block, 32 q-rows/wave (128 q-rows/block). K/V chunks of 64 staged
// in LDS (bf16, XOR-swizzled; V transposed), shared by all 4 waves. QK^T and
// PV via 16x16x32 MFMA; P through per-wave swizzled LDS. Online softmax;
// NO 1/sqrt(d) (per reference).
__global__ __launch_bounds__(256, 2)
void attn_kernel(const ushort* __restrict__ q, const ushort* __restrict__ k,
                 const ushort* __restrict__ v, ushort* __restrict__ o) {
  const int b = blockIdx.z, h = blockIdx.y;
  const int qt = (gridDim.x - 1) - blockIdx.x;   // longest first
  const int tid = threadIdx.x, wid = tid >> 6, lane = tid & 63;
  const int lo = lane & 15, hi = lane >> 4;
  const long bh = (long)b * T;
  const int qbase = qt * 128 + wid * 32;         // this wave's first q-row
  const int dch = qt * 2 + (wid >> 1);           // wave's diagonal chunk
  const int roff = 32 * (wid & 1);               // row offset in diag chunk
  __shared__ ushort Ks[64 * 64];                 // 8 KiB
  __shared__ ushort Vs[64 * 64];                 // 8 KiB (transposed)
  __shared__ ushort Ps[4][32 * 64];              // 16 KiB, per-wave P
  char* KsB = (char*)Ks;
  char* VsB = (char*)Vs;
  char* PsB = (char*)Ps[wid];

  bf16x8 qf[2][2];
  #pragma unroll
  for (int mf = 0; mf < 2; mf++)
    #pragma unroll
    for (int kh = 0; kh < 2; kh++)
      qf[mf][kh] = *(const bf16x8*)(q + (bh + qbase + mf * 16 + lo) * E +
                                    h * 64 + kh * 32 + hi * 8);
  f32x4 accO[2][4] = {};
  float m[2][4], lsum[2][4];
  #pragma unroll
  for (int a = 0; a < 2; a++)
    #pragma unroll
    for (int r = 0; r < 4; r++) { m[a][r] = -1e30f; lsum[a][r] = 0.f; }

  const ushort* kb = k + bh * E + h * 64;
  const ushort* vb = v + bh * E + h * 64;
  const int nch = qt * 2 + 2;

  for (int c = 0; c < nch; c++) {
    const long s0 = (long)c * 64;
    // ---- stage K chunk (swizzled rows): 64 rows x 8 uint4, 256 threads ----
    #pragma unroll
    for (int it = 0; it < 2; it++) {
      int idx = it * 256 + tid;                 // 0..511
      int key = idx >> 3, c8 = idx & 7;
      uint4 kv = *(const uint4*)(kb + (s0 + key) * E + c8 * 8);
      *(uint4*)(KsB + ((key * 128 + c8 * 16) ^ ((key & 7) << 4))) = kv;
    }
    // ---- stage V transposed (256 threads: 2 keys x 8 dims each) ----
    {
      const int key0 = (tid & 31) * 2, dim0 = (tid >> 5) * 8;
      uint4 v0 = *(const uint4*)(vb + (s0 + key0) * E + dim0);
      uint4 v1 = *(const uint4*)(vb + (s0 + key0 + 1) * E + dim0);
      const ushort* p0 = (const ushort*)&v0;
      const ushort* p1 = (const ushort*)&v1;
      #pragma unroll
      for (int j = 0; j < 8; j++) {
        const int dim = dim0 + j;
        ushort2 w;
        w.x = p0[j]; w.y = p1[j];
        *(ushort2*)(VsB + ((dim * 128 + key0 * 2) ^ ((dim & 7) << 4))) = w;
      }
    }
    __syncthreads();
    if (c <= dch) {
      const bool diag = (c == dch);
      bf16x8 kf[4][2];
      #pragma unroll
      for (int nf = 0; nf < 4; nf++)
        #pragma unroll
        for (int kh = 0; kh < 2; kh++) {
          const int key = nf * 16 + lo;
          kf[nf][kh] = *(const bf16x8*)(
              KsB + ((key * 128 + kh * 64 + hi * 16) ^ ((key & 7) << 4)));
        }
      #pragma unroll
      for (int mf = 0; mf < 2; mf++) {
        f32x4 s[4];
        #pragma unroll
        for (int nf = 0; nf < 4; nf++) {
          f32x4 z = {0.f, 0.f, 0.f, 0.f};
          z = __builtin_amdgcn_mfma_f32_16x16x32_bf16(qf[mf][0], kf[nf][0],
                                                      z, 0, 0, 0);
          z = __builtin_amdgcn_mfma_f32_16x16x32_bf16(qf[mf][1], kf[nf][1],
                                                      z, 0, 0, 0);
          s[nf] = z;
        }
        if (diag) {
          #pragma unroll
          for (int nf = 0; nf < 4; nf++)
            #pragma unroll
            for (int r = 0; r < 4; r++)
              if (nf * 16 + lo > roff + mf * 16 + hi * 4 + r)
                s[nf][r] = -1e30f;
        }
        #pragma unroll
        for (int r = 0; r < 4; r++) {
          float pm = fmaxf(fmaxf(s[0][r], s[1][r]), fmaxf(s[2][r], s[3][r]));
          #pragma unroll
          for (int msk = 1; msk < 16; msk <<= 1)
            pm = fmaxf(pm, __shfl_xor(pm, msk, 64));
          const float mn = fmaxf(m[mf][r], pm);
          const float sc = __expf(m[mf][r] - mn);
          m[mf][r] = mn;
          float p0 = __expf(s[0][r] - mn), p1 = __expf(s[1][r] - mn);
          float p2 = __expf(s[2][r] - mn), p3 = __expf(s[3][r] - mn);
          lsum[mf][r] = lsum[mf][r] * sc + (p0 + p1 + p2 + p3);
          #pragma unroll
          for (int nd = 0; nd < 4; nd++) accO[mf][nd][r] *= sc;
          const int ql = mf * 16 + hi * 4 + r;
          const int swz = (ql & 7) << 4;
          *(ushort*)(PsB + ((ql * 128 + (lo) * 2) ^ swz))      = f2b(p0);
          *(ushort*)(PsB + ((ql * 128 + (16 + lo) * 2) ^ swz)) = f2b(p1);
          *(ushort*)(PsB + ((ql * 128 + (32 + lo) * 2) ^ swz)) = f2b(p2);
          *(ushort*)(PsB + ((ql * 128 + (48 + lo) * 2) ^ swz)) = f2b(p3);
        }
      }
      asm volatile("s_waitcnt lgkmcnt(0)" ::: "memory");  // P w->r, same wave
      #pragma unroll
      for (int ks = 0; ks < 2; ks++) {
        bf16x8 pa[2];
        #pragma unroll
        for (int mf = 0; mf < 2; mf++) {
          const int ql = mf * 16 + lo;
          pa[mf] = *(const bf16x8*)(
              PsB + ((ql * 128 + ks * 64 + hi * 16) ^ ((ql & 7) << 4)));
        }
        #pragma unroll
        for (int nd = 0; nd < 4; nd++) {
          const int dim = nd * 16 + lo;
          bf16x8 vf = *(const bf16x8*)(
              VsB + ((dim * 128 + ks * 64 + hi * 16) ^ ((dim & 7) << 4)));
          #pragma unroll
          for (int mf = 0; mf < 2; mf++)
            accO[mf][nd] = __builtin_amdgcn_mfma_f32_16x16x32_bf16(
                pa[mf], vf, accO[mf][nd], 0, 0, 0);
        }
      }
    }
    __syncthreads();
  }
  // ---- finalize: 1/l, stage O in own P region, coalesced store ----
  #pragma unroll
  for (int mf = 0; mf < 2; mf++)
    #pragma unroll
    for (int r = 0; r < 4; r++) {
      float l = lsum[mf][r];
      #pragma unroll
      for (int msk = 1; msk < 16; msk <<= 1) l += __shfl_xor(l, msk, 64);
      lsum[mf][r] = 1.0f / l;
    }
  #pragma unroll
  for (int mf = 0; mf < 2; mf++)
    #pragma unroll
    for (int nd = 0; nd < 4; nd++)
      #pragma unroll
      for (int r = 0; r < 4; r++) {
        const int ql = mf * 16 + hi * 4 + r, dim = nd * 16 + lo;
        *(ushort*)(PsB + ql * 128 + dim * 2) =
            f2b(accO[mf][nd][r] * lsum[mf][r]);
      }
  asm volatile("s_waitcnt lgkmcnt(0)" ::: "memory");  // O w->r, same wave
  #pragma unroll
  for (int it = 0; it < 4; it++) {
    const int idx = it * 64 + lane;
    const int row = idx >> 3, c8 = idx & 7;           // row 0..31
    uint4 val = *(const uint4*)(PsB + row * 128 + c8 * 16);
    *(uint4*)(o + (bh + qbase + row) * E + h * 64 + c8 * 8) = val;
  }
}

// --------------------------------------------------------------- logits ----
__global__ __launch_bounds__(256)
void logits_kernel(const ushort* __restrict__ xf, const ushort* __restrict__ WfT,
                   const float* __restrict__ bf, float* __restrict__ out) {
  __shared__ float xs[8][E];
  const int row0 = blockIdx.x * 8, tid = threadIdx.x;
  #pragma unroll
  for (int i = 0; i < 4; i++) {
    int idx = i * 256 + tid;
    int r = idx >> 7, c4 = idx & 127;
    ushort4 u = ((const ushort4*)(xf + (long)(row0 + r) * E))[c4];
    float4 f;
    f.x = b2f(u.x); f.y = b2f(u.y); f.z = b2f(u.z); f.w = b2f(u.w);
    *(float4*)&xs[r][c4 * 4] = f;
  }
  __syncthreads();
  const int r = tid >> 5, c = tid & 31;
  float acc = 0.f;
  for (int e8 = 0; e8 < 64; e8++) {
    uint4 w = *(const uint4*)(WfT + (long)c * E + e8 * 8);
    const ushort* ws = (const ushort*)&w;
    #pragma unroll
    for (int j = 0; j < 8; j++) acc += xs[r][e8 * 8 + j] * b2f(ws[j]);
  }
  out[(long)(row0 + r) * V + c] = acc + bf[c];
}

}  // namespace

// ------------------------------------------------------------- launcher ----
extern "C" void kernel_launch(void* const* d_in, const int* in_sizes, int n_in,
                              void* d_out, int out_size, void* d_ws,
                              size_t ws_size, hipStream_t stream) {
  const int*   tokens = (const int*)d_in[0];
  const float* emb    = (const float*)d_in[1];
  const float* pos    = (const float*)d_in[2];
  const float* Wq     = (const float*)d_in[3];
  const float* Wk     = (const float*)d_in[4];
  const float* Wv     = (const float*)d_in[5];
  const float* Wo     = (const float*)d_in[6];
  const float* bo     = (const float*)d_in[7];
  const float* ln1g   = (const float*)d_in[8];
  const float* ln1b   = (const float*)d_in[9];
  const float* ln2g   = (const float*)d_in[10];
  const float* ln2b   = (const float*)d_in[11];
  const float* W1     = (const float*)d_in[12];
  const float* b1     = (const float*)d_in[13];
  const float* W2     = (const float*)d_in[14];
  const float* b2     = (const float*)d_in[15];
  const float* lnfg   = (const float*)d_in[16];
  const float* lnfb   = (const float*)d_in[17];
  const float* Wf     = (const float*)d_in[18];
  const float* bf     = (const float*)d_in[19];
  float* out = (float*)d_out;

  // ---- workspace layout ----
  char* p = (char*)d_ws;
  float*  x   = (float*)p;           p += S * 4;          // fp32 residual
  ushort* hb  = (ushort*)p;          p += S * 2;
  ushort* qbb = (ushort*)p;          p += S * 2;
  ushort* kbb = (ushort*)p;          p += S * 2;
  ushort* vbb = (ushort*)p;          p += S * 2;
  const long WSZ = (long)L * E * E;
  ushort* wqT = (ushort*)p;          p += WSZ * 2;
  ushort* wkT = (ushort*)p;          p += WSZ * 2;
  ushort* wvT = (ushort*)p;          p += WSZ * 2;
  ushort* woT = (ushort*)p;          p += WSZ * 2;
  ushort* w1T = (ushort*)p;          p += WSZ * 2;
  ushort* w2T = (ushort*)p;          p += WSZ * 2;
  ushort* wfT = (ushort*)p;          p += (long)E * V * 2;

  // ---- weight conversion (every call; ~60 us) ----
  wconv_kernel<<<dim3(16, 2, L * H), 256, 0, stream>>>(Wq, wqT, E, HD);
  wconv_kernel<<<dim3(16, 2, L * H), 256, 0, stream>>>(Wk, wkT, E, HD);
  wconv_kernel<<<dim3(16, 2, L * H), 256, 0, stream>>>(Wv, wvT, E, HD);
  wconv_kernel<<<dim3(16, 16, L), 256, 0, stream>>>(Wo, woT, E, E);
  wconv_kernel<<<dim3(16, 16, L), 256, 0, stream>>>(W1, w1T, E, E);
  wconv_kernel<<<dim3(16, 16, L), 256, 0, stream>>>(W2, w2T, E, E);
  wconv_kernel<<<dim3(16, 1, 1), 256, 0, stream>>>(Wf, wfT, E, V);

  embed_kernel<<<(BT * (E / 4) + 255) / 256, 256, 0, stream>>>(tokens, emb,
                                                               pos, x);

  const dim3 gg(BT / 128, E / 128);   // 128 x 4
  const dim3 ga(T / 128, H, B);       // 8 x 8 x 16, 256 threads (4 waves)

  for (int l = 0; l < L; l++) {
    const long wo = (long)l * E * E;
    ln_kernel<<<BT, 128, 0, stream>>>(x, ln1g + l * E, ln1b + l * E, hb);
    bgemm_kernel<0><<<gg, 256, 0, stream>>>(hb, wqT + wo, nullptr, nullptr,
                                            qbb);
    bgemm_kernel<0><<<gg, 256, 0, stream>>>(hb, wkT + wo, nullptr, nullptr,
                                            kbb);
    bgemm_kernel<0><<<gg, 256, 0, stream>>>(hb, wvT + wo, nullptr, nullptr,
                                            vbb);
    attn_kernel<<<ga, 256, 0, stream>>>(qbb, kbb, vbb, hb);
    bgemm_kernel<1><<<gg, 256, 0, stream>>>(hb, woT + wo, bo + l * E, x, x);
    ln_kernel<<<BT, 128, 0, stream>>>(x, ln2g + l * E, ln2b + l * E, hb);
    bgemm_kernel<2><<<gg, 256, 0, stream>>>(hb, w1T + wo, b1 + l * E, nullptr,
                                            qbb);
    bgemm_kernel<1><<<gg, 256, 0, stream>>>(qbb, w2T + wo, b2 + l * E, x, x);
  }

  ln_kernel<<<BT, 128, 0, stream>>>(x, lnfg, lnfb, hb);
  logits_kernel<<<BT / 8, 256, 0, stream>>>(hb, wfT, bf, out);
}

// Round 7
// 1557.362 us; speedup vs baseline: 10.2149x; 1.0130x over previous
//
#include <hip/hip_runtime.h>
#include <hip/hip_bf16.h>

namespace {

constexpr int B = 16, T = 1024, E = 512, H = 8, L = 6, V = 32, HD = 64;
constexpr int BT = B * T;
constexpr long S = (long)BT * E;
constexpr int QS = 1536;               // fused QKV row stride

typedef __attribute__((ext_vector_type(8))) short bf16x8;
typedef __attribute__((ext_vector_type(4))) float f32x4;

__device__ inline float b2f(ushort u) {
  union { unsigned u; float f; } v; v.u = (unsigned)u << 16; return v.f;
}
__device__ inline ushort f2b(float f) {   // RNE fp32->bf16
  union { float f; unsigned u; } v; v.f = f;
  unsigned r = v.u + 0x7FFFu + ((v.u >> 16) & 1u);
  return (ushort)(r >> 16);
}
__device__ inline void gl_lds16(const ushort* g, ushort* lds) {
  __builtin_amdgcn_global_load_lds(
      (const __attribute__((address_space(1))) void*)g,
      (__attribute__((address_space(3))) void*)lds, 16, 0, 0);
}

// ---------------------------------------------------------------- embed ----
__global__ void embed_kernel(const int* __restrict__ tokens,
                             const float* __restrict__ emb,
                             const float* __restrict__ pos,
                             float* __restrict__ x) {
  int idx = blockIdx.x * blockDim.x + threadIdx.x;
  constexpr int TOT = BT * (E / 4);
  if (idx >= TOT) return;
  int row = idx >> 7, c4 = idx & 127;
  int t = row & (T - 1);
  int tok = tokens[row];
  float4 a = reinterpret_cast<const float4*>(emb + (long)tok * E)[c4];
  float4 p = reinterpret_cast<const float4*>(pos + (long)t * E)[c4];
  float4 r;
  r.x = a.x + p.x; r.y = a.y + p.y; r.z = a.z + p.z; r.w = a.w + p.w;
  reinterpret_cast<float4*>(x + (long)row * E)[c4] = r;
}

// --------------------------------------------- weight transpose -> bf16 ----
// in: z-panels of [K][Nn] f32 ; out: [Nn][K] bf16 panels at
//   (z/ppl)*layer_stride + off + (z%ppl)*(Nn*K)
__global__ __launch_bounds__(256)
void wconv_kernel(const float* __restrict__ in, ushort* __restrict__ out,
                  int K, int Nn, int ppl, long layer_stride, long off) {
  const int z = blockIdx.z;
  const long pin = (long)z * K * Nn;
  const long pout = (long)(z / ppl) * layer_stride + off +
                    (long)(z % ppl) * Nn * K;
  __shared__ float t[32][33];
  const int k0 = blockIdx.x * 32, n0 = blockIdx.y * 32;
  const int tid = threadIdx.x, r = tid >> 5, c = tid & 31;
  #pragma unroll
  for (int i = 0; i < 4; i++)
    t[r + i * 8][c] = in[pin + (long)(k0 + r + i * 8) * Nn + n0 + c];
  __syncthreads();
  #pragma unroll
  for (int i = 0; i < 4; i++)
    out[pout + (long)(n0 + r + i * 8) * K + k0 + c] = f2b(t[c][r + i * 8]);
}

// ------------------------------------------------- layernorm (bf16 out) ----
__global__ __launch_bounds__(128)
void ln_kernel(const float* __restrict__ x, const float* __restrict__ g,
               const float* __restrict__ b, ushort* __restrict__ out) {
  int row = blockIdx.x, tid = threadIdx.x;
  float4 v = reinterpret_cast<const float4*>(x + (long)row * E)[tid];
  float s = v.x + v.y + v.z + v.w;
  #pragma unroll
  for (int off = 32; off > 0; off >>= 1) s += __shfl_down(s, off, 64);
  __shared__ float r1[2], r2[2];
  int lane = tid & 63, wid = tid >> 6;
  if (lane == 0) r1[wid] = s;
  __syncthreads();
  float mean = (r1[0] + r1[1]) * (1.0f / E);
  float4 d;
  d.x = v.x - mean; d.y = v.y - mean; d.z = v.z - mean; d.w = v.w - mean;
  float s2 = d.x * d.x + d.y * d.y + d.z * d.z + d.w * d.w;
  #pragma unroll
  for (int off = 32; off > 0; off >>= 1) s2 += __shfl_down(s2, off, 64);
  if (lane == 0) r2[wid] = s2;
  __syncthreads();
  float rstd = rsqrtf((r2[0] + r2[1]) * (1.0f / E) + 1e-5f);
  float4 gg = reinterpret_cast<const float4*>(g)[tid];
  float4 bb = reinterpret_cast<const float4*>(b)[tid];
  ushort4 o;
  o.x = f2b(d.x * rstd * gg.x + bb.x);
  o.y = f2b(d.y * rstd * gg.y + bb.y);
  o.z = f2b(d.z * rstd * gg.z + bb.z);
  o.w = f2b(d.w * rstd * gg.w + bb.w);
  reinterpret_cast<ushort4*>(out + (long)row * E)[tid] = o;
}

// ------------------------------------------------------------ bf16 GEMM ----
// C[M=BT][Nl] = A[M][512](bf16) @ Bt[Nl][512](bf16, [N][K])
// MODE 0: C=bf16(acc)  1: C=f32(acc+bias+res)  2: C=bf16(relu(acc+bias))
template <int MODE>
__global__ __launch_bounds__(256, 2)
void bgemm_kernel(const ushort* __restrict__ A, const ushort* __restrict__ Bt,
                  const float* __restrict__ bias, const float* __restrict__ res,
                  void* __restrict__ Cout, int Nl) {
  constexpr int K = 512;
  __shared__ ushort As[128][32];
  __shared__ ushort Bs[128][32];
  const int tid = threadIdx.x, lane = tid & 63, wid = tid >> 6;
  const int bm = blockIdx.x * 128, bn = blockIdx.y * 128;
  const int wm = (wid >> 1) * 64, wn = (wid & 1) * 64;
  const int lo = lane & 15, hi = lane >> 4;
  const int arow = lane >> 2, acol = (lane & 3) * 8;
  f32x4 acc[4][4] = {};
  for (int k0 = 0; k0 < K; k0 += 32) {
    #pragma unroll
    for (int i = 0; i < 2; i++) {
      int seg = wid * 2 + i;
      gl_lds16(A + (long)(bm + seg * 16 + arow) * K + k0 + acol,
               &As[seg * 16][0]);
      gl_lds16(Bt + (long)(bn + seg * 16 + arow) * K + k0 + acol,
               &Bs[seg * 16][0]);
    }
    __syncthreads();
    bf16x8 af[4], bfr[4];
    #pragma unroll
    for (int mi = 0; mi < 4; mi++)
      af[mi] = *(const bf16x8*)&As[wm + mi * 16 + lo][hi * 8];
    #pragma unroll
    for (int ni = 0; ni < 4; ni++)
      bfr[ni] = *(const bf16x8*)&Bs[wn + ni * 16 + lo][hi * 8];
    #pragma unroll
    for (int mi = 0; mi < 4; mi++)
      #pragma unroll
      for (int ni = 0; ni < 4; ni++)
        acc[mi][ni] = __builtin_amdgcn_mfma_f32_16x16x32_bf16(
            af[mi], bfr[ni], acc[mi][ni], 0, 0, 0);
    __syncthreads();
  }
  #pragma unroll
  for (int mi = 0; mi < 4; mi++) {
    #pragma unroll
    for (int ni = 0; ni < 4; ni++) {
      const int gn = bn + wn + ni * 16 + lo;
      const float bv = (MODE >= 1) ? bias[gn] : 0.f;
      #pragma unroll
      for (int r = 0; r < 4; r++) {
        const long gm = bm + wm + mi * 16 + hi * 4 + r;
        float vv = acc[mi][ni][r];
        if (MODE == 0) {
          ((ushort*)Cout)[gm * Nl + gn] = f2b(vv);
        } else if (MODE == 1) {
          ((float*)Cout)[gm * Nl + gn] = vv + bv + res[gm * Nl + gn];
        } else {
          ((ushort*)Cout)[gm * Nl + gn] = f2b(fmaxf(vv + bv, 0.f));
        }
      }
    }
  }
}

// ------------------------------------------------------- MFMA attention ----
// 4 waves/block, 32 q-rows/wave (128 q-rows/block). K/V chunks of 64 in
// double-buffered LDS (bf16, XOR-swizzled; V transposed); next chunk's
// global loads issued into registers BEFORE compute, ds_written after
// (T14), one barrier per round. QK^T and PV via 16x16x32 MFMA; P through
// per-wave swizzled LDS. Online softmax; NO 1/sqrt(d) (per reference).
// q/k/v packed in one [BT][1536] buffer (offs 0/512/1024).
__global__ __launch_bounds__(256, 2)
void attn_kernel(const ushort* __restrict__ qkv, ushort* __restrict__ o) {
  const int b = blockIdx.z, h = blockIdx.y;
  const int qt = (gridDim.x - 1) - blockIdx.x;   // longest first
  const int tid = threadIdx.x, wid = tid >> 6, lane = tid & 63;
  const int lo = lane & 15, hi = lane >> 4;
  const long bh = (long)b * T;
  const int qbase = qt * 128 + wid * 32;         // this wave's first q-row
  const int dch = qt * 2 + (wid >> 1);           // wave's diagonal chunk
  const int roff = 32 * (wid & 1);               // row offset in diag chunk
  __shared__ ushort Ks[2][64 * 64];              // 16 KiB (2 bufs)
  __shared__ ushort Vs[2][64 * 64];              // 16 KiB (transposed)
  __shared__ ushort Ps[4][32 * 64];              // 16 KiB, per-wave P
  char* PsB = (char*)Ps[wid];

  bf16x8 qf[2][2];
  #pragma unroll
  for (int mf = 0; mf < 2; mf++)
    #pragma unroll
    for (int kh = 0; kh < 2; kh++)
      qf[mf][kh] = *(const bf16x8*)(qkv + (bh + qbase + mf * 16 + lo) * QS +
                                    h * 64 + kh * 32 + hi * 8);
  f32x4 accO[2][4] = {};
  float m[2][4], lsum[2][4];
  #pragma unroll
  for (int a = 0; a < 2; a++)
    #pragma unroll
    for (int r = 0; r < 4; r++) { m[a][r] = -1e30f; lsum[a][r] = 0.f; }

  const ushort* kb = qkv + bh * QS + 512 + h * 64;
  const ushort* vb = qkv + bh * QS + 1024 + h * 64;
  const int nch = qt * 2 + 2;

  // prefetch registers + stage helpers
  uint4 kpre[2], vpre[2];
  const int kkey0 = tid >> 3, kc8 = tid & 7;          // K: 2 rows/thread
  const int vkey0 = (tid & 31) * 2, vdim0 = (tid >> 5) * 8;
  auto LOADC = [&](int cc) {
    const long s0 = (long)cc * 64;
    kpre[0] = *(const uint4*)(kb + (s0 + kkey0) * QS + kc8 * 8);
    kpre[1] = *(const uint4*)(kb + (s0 + kkey0 + 32) * QS + kc8 * 8);
    vpre[0] = *(const uint4*)(vb + (s0 + vkey0) * QS + vdim0);
    vpre[1] = *(const uint4*)(vb + (s0 + vkey0 + 1) * QS + vdim0);
  };
  auto WRITEC = [&](int buf) {
    char* KsB = (char*)Ks[buf];
    char* VsB = (char*)Vs[buf];
    #pragma unroll
    for (int it = 0; it < 2; it++) {
      const int key = kkey0 + it * 32;
      *(uint4*)(KsB + ((key * 128 + kc8 * 16) ^ ((key & 7) << 4))) = kpre[it];
    }
    const ushort* p0 = (const ushort*)&vpre[0];
    const ushort* p1 = (const ushort*)&vpre[1];
    #pragma unroll
    for (int j = 0; j < 8; j++) {
      const int dim = vdim0 + j;
      ushort2 w; w.x = p0[j]; w.y = p1[j];
      *(ushort2*)(VsB + ((dim * 128 + vkey0 * 2) ^ ((dim & 7) << 4))) = w;
    }
  };

  LOADC(0);
  WRITEC(0);
  __syncthreads();

  for (int c = 0; c < nch; c++) {
    const int cur = c & 1;
    if (c + 1 < nch) LOADC(c + 1);           // hide HBM under compute
    if (c <= dch) {
      char* KsB = (char*)Ks[cur];
      char* VsB = (char*)Vs[cur];
      const bool diag = (c == dch);
      bf16x8 kf[4][2];
      #pragma unroll
      for (int nf = 0; nf < 4; nf++)
        #pragma unroll
        for (int kh = 0; kh < 2; kh++) {
          const int key = nf * 16 + lo;
          kf[nf][kh] = *(const bf16x8*)(
              KsB + ((key * 128 + kh * 64 + hi * 16) ^ ((key & 7) << 4)));
        }
      #pragma unroll
      for (int mf = 0; mf < 2; mf++) {
        f32x4 s[4];
        __builtin_amdgcn_s_setprio(1);
        #pragma unroll
        for (int nf = 0; nf < 4; nf++) {
          f32x4 z = {0.f, 0.f, 0.f, 0.f};
          z = __builtin_amdgcn_mfma_f32_16x16x32_bf16(qf[mf][0], kf[nf][0],
                                                      z, 0, 0, 0);
          z = __builtin_amdgcn_mfma_f32_16x16x32_bf16(qf[mf][1], kf[nf][1],
                                                      z, 0, 0, 0);
          s[nf] = z;
        }
        __builtin_amdgcn_s_setprio(0);
        if (diag) {
          #pragma unroll
          for (int nf = 0; nf < 4; nf++)
            #pragma unroll
            for (int r = 0; r < 4; r++)
              if (nf * 16 + lo > roff + mf * 16 + hi * 4 + r)
                s[nf][r] = -1e30f;
        }
        #pragma unroll
        for (int r = 0; r < 4; r++) {
          float pm = fmaxf(fmaxf(s[0][r], s[1][r]), fmaxf(s[2][r], s[3][r]));
          #pragma unroll
          for (int msk = 1; msk < 16; msk <<= 1)
            pm = fmaxf(pm, __shfl_xor(pm, msk, 64));
          const float mn = fmaxf(m[mf][r], pm);
          const float sc = __expf(m[mf][r] - mn);
          m[mf][r] = mn;
          float p0 = __expf(s[0][r] - mn), p1 = __expf(s[1][r] - mn);
          float p2 = __expf(s[2][r] - mn), p3 = __expf(s[3][r] - mn);
          lsum[mf][r] = lsum[mf][r] * sc + (p0 + p1 + p2 + p3);
          #pragma unroll
          for (int nd = 0; nd < 4; nd++) accO[mf][nd][r] *= sc;
          const int ql = mf * 16 + hi * 4 + r;
          const int swz = (ql & 7) << 4;
          *(ushort*)(PsB + ((ql * 128 + (lo) * 2) ^ swz))      = f2b(p0);
          *(ushort*)(PsB + ((ql * 128 + (16 + lo) * 2) ^ swz)) = f2b(p1);
          *(ushort*)(PsB + ((ql * 128 + (32 + lo) * 2) ^ swz)) = f2b(p2);
          *(ushort*)(PsB + ((ql * 128 + (48 + lo) * 2) ^ swz)) = f2b(p3);
        }
      }
      asm volatile("s_waitcnt lgkmcnt(0)" ::: "memory");  // P w->r, same wave
      #pragma unroll
      for (int ks = 0; ks < 2; ks++) {
        bf16x8 pa[2];
        #pragma unroll
        for (int mf = 0; mf < 2; mf++) {
          const int ql = mf * 16 + lo;
          pa[mf] = *(const bf16x8*)(
              PsB + ((ql * 128 + ks * 64 + hi * 16) ^ ((ql & 7) << 4)));
        }
        __builtin_amdgcn_s_setprio(1);
        #pragma unroll
        for (int nd = 0; nd < 4; nd++) {
          const int dim = nd * 16 + lo;
          bf16x8 vf = *(const bf16x8*)(
              VsB + ((dim * 128 + ks * 64 + hi * 16) ^ ((dim & 7) << 4)));
          #pragma unroll
          for (int mf = 0; mf < 2; mf++)
            accO[mf][nd] = __builtin_amdgcn_mfma_f32_16x16x32_bf16(
                pa[mf], vf, accO[mf][nd], 0, 0, 0);
        }
        __builtin_amdgcn_s_setprio(0);
      }
    }
    if (c + 1 < nch) WRITEC(cur ^ 1);        // stage next into other buffer
    __syncthreads();
  }
  // ---- finalize: 1/l, stage O in own P region, coalesced store ----
  #pragma unroll
  for (int mf = 0; mf < 2; mf++)
    #pragma unroll
    for (int r = 0; r < 4; r++) {
      float l = lsum[mf][r];
      #pragma unroll
      for (int msk = 1; msk < 16; msk <<= 1) l += __shfl_xor(l, msk, 64);
      lsum[mf][r] = 1.0f / l;
    }
  #pragma unroll
  for (int mf = 0; mf < 2; mf++)
    #pragma unroll
    for (int nd = 0; nd < 4; nd++)
      #pragma unroll
      for (int r = 0; r < 4; r++) {
        const int ql = mf * 16 + hi * 4 + r, dim = nd * 16 + lo;
        *(ushort*)(PsB + ql * 128 + dim * 2) =
            f2b(accO[mf][nd][r] * lsum[mf][r]);
      }
  asm volatile("s_waitcnt lgkmcnt(0)" ::: "memory");  // O w->r, same wave
  #pragma unroll
  for (int it = 0; it < 4; it++) {
    const int idx = it * 64 + lane;
    const int row = idx >> 3, c8 = idx & 7;           // row 0..31
    uint4 val = *(const uint4*)(PsB + row * 128 + c8 * 16);
    *(uint4*)(o + (bh + qbase + row) * E + h * 64 + c8 * 8) = val;
  }
}

// --------------------------------------------------------------- logits ----
__global__ __launch_bounds__(256)
void logits_kernel(const ushort* __restrict__ xf, const ushort* __restrict__ WfT,
                   const float* __restrict__ bf, float* __restrict__ out) {
  __shared__ float xs[8][E];
  const int row0 = blockIdx.x * 8, tid = threadIdx.x;
  #pragma unroll
  for (int i = 0; i < 4; i++) {
    int idx = i * 256 + tid;
    int r = idx >> 7, c4 = idx & 127;
    ushort4 u = ((const ushort4*)(xf + (long)(row0 + r) * E))[c4];
    float4 f;
    f.x = b2f(u.x); f.y = b2f(u.y); f.z = b2f(u.z); f.w = b2f(u.w);
    *(float4*)&xs[r][c4 * 4] = f;
  }
  __syncthreads();
  const int r = tid >> 5, c = tid & 31;
  float acc = 0.f;
  for (int e8 = 0; e8 < 64; e8++) {
    uint4 w = *(const uint4*)(WfT + (long)c * E + e8 * 8);
    const ushort* ws = (const ushort*)&w;
    #pragma unroll
    for (int j = 0; j < 8; j++) acc += xs[r][e8 * 8 + j] * b2f(ws[j]);
  }
  out[(long)(row0 + r) * V + c] = acc + bf[c];
}

}  // namespace

// ------------------------------------------------------------- launcher ----
extern "C" void kernel_launch(void* const* d_in, const int* in_sizes, int n_in,
                              void* d_out, int out_size, void* d_ws,
                              size_t ws_size, hipStream_t stream) {
  const int*   tokens = (const int*)d_in[0];
  const float* emb    = (const float*)d_in[1];
  const float* pos    = (const float*)d_in[2];
  const float* Wq     = (const float*)d_in[3];
  const float* Wk     = (const float*)d_in[4];
  const float* Wv     = (const float*)d_in[5];
  const float* Wo     = (const float*)d_in[6];
  const float* bo     = (const float*)d_in[7];
  const float* ln1g   = (const float*)d_in[8];
  const float* ln1b   = (const float*)d_in[9];
  const float* ln2g   = (const float*)d_in[10];
  const float* ln2b   = (const float*)d_in[11];
  const float* W1     = (const float*)d_in[12];
  const float* b1     = (const float*)d_in[13];
  const float* W2     = (const float*)d_in[14];
  const float* b2     = (const float*)d_in[15];
  const float* lnfg   = (const float*)d_in[16];
  const float* lnfb   = (const float*)d_in[17];
  const float* Wf     = (const float*)d_in[18];
  const float* bf     = (const float*)d_in[19];
  float* out = (float*)d_out;

  // ---- workspace layout ----
  char* p = (char*)d_ws;
  float*  x    = (float*)p;          p += S * 4;           // fp32 residual
  ushort* hb   = (ushort*)p;         p += S * 2;           // LN out / attn out
  ushort* qkvb = (ushort*)p;         p += (long)BT * QS * 2;  // fused QKV
  const long WSZ = (long)L * E * E;
  ushort* wqkvT = (ushort*)p;        p += (long)L * QS * E * 2;
  ushort* woT  = (ushort*)p;         p += WSZ * 2;
  ushort* w1T  = (ushort*)p;         p += WSZ * 2;
  ushort* w2T  = (ushort*)p;         p += WSZ * 2;
  ushort* wfT  = (ushort*)p;         p += (long)E * V * 2;

  const long QLS = (long)QS * E;     // per-layer fused weight stride

  // ---- weight conversion (every call; ~60 us) ----
  wconv_kernel<<<dim3(16, 2, L * H), 256, 0, stream>>>(Wq, wqkvT, E, HD, H,
                                                       QLS, 0);
  wconv_kernel<<<dim3(16, 2, L * H), 256, 0, stream>>>(Wk, wqkvT, E, HD, H,
                                                       QLS, (long)512 * E);
  wconv_kernel<<<dim3(16, 2, L * H), 256, 0, stream>>>(Wv, wqkvT, E, HD, H,
                                                       QLS, (long)1024 * E);
  wconv_kernel<<<dim3(16, 16, L), 256, 0, stream>>>(Wo, woT, E, E, 1,
                                                    (long)E * E, 0);
  wconv_kernel<<<dim3(16, 16, L), 256, 0, stream>>>(W1, w1T, E, E, 1,
                                                    (long)E * E, 0);
  wconv_kernel<<<dim3(16, 16, L), 256, 0, stream>>>(W2, w2T, E, E, 1,
                                                    (long)E * E, 0);
  wconv_kernel<<<dim3(16, 1, 1), 256, 0, stream>>>(Wf, wfT, E, V, 1,
                                                   (long)E * V, 0);

  embed_kernel<<<(BT * (E / 4) + 255) / 256, 256, 0, stream>>>(tokens, emb,
                                                               pos, x);

  const dim3 gq(BT / 128, QS / 128);  // 128 x 12 (fused QKV)
  const dim3 gg(BT / 128, E / 128);   // 128 x 4
  const dim3 ga(T / 128, H, B);       // 8 x 8 x 16, 256 threads (4 waves)

  for (int l = 0; l < L; l++) {
    const long wo = (long)l * E * E;
    ln_kernel<<<BT, 128, 0, stream>>>(x, ln1g + l * E, ln1b + l * E, hb);
    bgemm_kernel<0><<<gq, 256, 0, stream>>>(hb, wqkvT + l * QLS, nullptr,
                                            nullptr, qkvb, QS);
    attn_kernel<<<ga, 256, 0, stream>>>(qkvb, hb);
    bgemm_kernel<1><<<gg, 256, 0, stream>>>(hb, woT + wo, bo + l * E, x, x,
                                            E);
    ln_kernel<<<BT, 128, 0, stream>>>(x, ln2g + l * E, ln2b + l * E, hb);
    bgemm_kernel<2><<<gg, 256, 0, stream>>>(hb, w1T + wo, b1 + l * E, nullptr,
                                            qkvb, E);
    bgemm_kernel<1><<<gg, 256, 0, stream>>>((ushort*)qkvb, w2T + wo,
                                            b2 + l * E, x, x, E);
  }

  ln_kernel<<<BT, 128, 0, stream>>>(x, lnfg, lnfb, hb);
  logits_kernel<<<BT / 8, 256, 0, stream>>>(hb, wfT, bf, out);
}